// Round 6
// baseline (82.065 us; speedup 1.0000x reference)
//
#include <hip/hip_runtime.h>
#include <hip/hip_bf16.h>

typedef __bf16 bf16x8 __attribute__((ext_vector_type(8)));
typedef float  f32x4  __attribute__((ext_vector_type(4)));

#define MFMA32(acc, a, b) acc = __builtin_amdgcn_mfma_f32_16x16x32_bf16(a, b, acc, 0, 0, 0)
#define LD4(p) (*(const float4*)(p))

__device__ __forceinline__ bf16x8 cvt8(float4 a, float4 b) {
  bf16x8 r;
  r[0] = (__bf16)a.x; r[1] = (__bf16)a.y; r[2] = (__bf16)a.z; r[3] = (__bf16)a.w;
  r[4] = (__bf16)b.x; r[5] = (__bf16)b.y; r[6] = (__bf16)b.z; r[7] = (__bf16)b.w;
  return r;
}

// DPP helpers. row_ror:N = 0x120|N (16-lane rotate); quad_perm xor2 = 0x4E,
// xor1 = 0xB1. bound_ctrl=true (never OOB for these patterns).
template <int CTRL>
__device__ __forceinline__ float dpp_mov(float x) {
  int yi = __builtin_amdgcn_update_dpp(0, __builtin_bit_cast(int, x), CTRL, 0xF, 0xF, true);
  return __builtin_bit_cast(float, yi);
}
template <int CTRL>
__device__ __forceinline__ float dpp_fadd(float x) { return x + dpp_mov<CTRL>(x); }
template <int CTRL>
__device__ __forceinline__ float dpp_fmax(float x) { return fmaxf(x, dpp_mov<CTRL>(x)); }

// W1frag [ks=4][mt=4][lane][j=8]: A-frag of W1^T:
//   = W1[(ks*32 + (lane>>4)*8 + j)][mt*16 + (lane&15)]
// W2frag [ks2=2][mt2=4][lane][j=8]: A-frag of W2^T with PERMUTED k-axis
//   rho(ks2,g,j) = (ks2*2 + (j>>2))*16 + g*4 + (j&3)   (g = lane>>4)
//   = W2[rho][mt2*16 + (lane&15)]
// Same rho used when building layer-2 B-frags from in-register layer-1 accs.
__global__ void prep_frags(const float* __restrict__ W1,
                           const float* __restrict__ W2,
                           __bf16* __restrict__ wf) {
  int idx = blockIdx.x * 256 + threadIdx.x;
  if (idx < 8192) {
    int j = idx & 7, lane = (idx >> 3) & 63, mt = (idx >> 9) & 3, ks = idx >> 11;
    int i = ks * 32 + ((lane >> 4) << 3) + j;
    int col = mt * 16 + (lane & 15);
    wf[idx] = (__bf16)W1[i * 64 + col];
  } else if (idx < 12288) {
    int t = idx - 8192;
    int j = t & 7, lane = (t >> 3) & 63, mt2 = (t >> 9) & 3, ks2 = (t >> 11) & 1;
    int g = (lane >> 4) & 3;
    int rho = (ks2 * 2 + (j >> 2)) * 16 + g * 4 + (j & 3);
    wf[idx] = (__bf16)W2[rho * 64 + mt2 * 16 + (lane & 15)];
  }
}

// Issue the 12 float4 gather loads for node XN (neighbors XI0/XI1, degree XD)
// into the loop-carried raw regs. Consumed (cvt'd) at the TOP of the next
// iteration -> loads stay in flight across ~score+softmax+output+cvt+layer1.
#define ISSUE_RAW(XN, XD, XI0, XI1) do {                                      \
    const float* up_ = emb + (long)(XN) * 64 + g * 8;                         \
    ru0 = LD4(up_); ru1 = LD4(up_ + 4); ru2 = LD4(up_ + 32); ru3 = LD4(up_ + 36); \
    const int a0_ = ((lr) < (XD)) ? (XI0) : (XN);                             \
    const float* p0_ = emb + (long)a0_ * 64 + g * 8;                          \
    re0a = LD4(p0_); re0b = LD4(p0_ + 4); re0c = LD4(p0_ + 32); re0d = LD4(p0_ + 36); \
    if ((XD) > 16) {                                                          \
      const int a1_ = (16 + (lr) < (XD)) ? (XI1) : (XN);                      \
      const float* p1_ = emb + (long)a1_ * 64 + g * 8;                        \
      re1a = LD4(p1_); re1b = LD4(p1_ + 4); re1c = LD4(p1_ + 32); re1d = LD4(p1_ + 36); \
    }                                                                         \
  } while (0)

// One wave per node, 512 threads = 8 waves/block. No min-waves bound (R3/R4:
// any bound makes the compiler spill or rematerialize the register-resident
// fragments). Gather is software-pipelined one node ahead.
// LDS: [0,16384) W1frag  [16384,24576) W2frag
//      [24576,24832) b1 f32  [24832,25088) b2 f32  [25088,25344) w3 f32
__global__ __launch_bounds__(512) void graph_agg(
    const float* __restrict__ emb,
    const float* __restrict__ b1g,
    const float* __restrict__ b2g,
    const float* __restrict__ w3g,
    const float* __restrict__ b3g,
    const int* __restrict__ vn,
    const int* __restrict__ ni,
    const int* __restrict__ nd,
    const __bf16* __restrict__ wf,
    float* __restrict__ out,
    int N) {
  __shared__ __align__(16) unsigned char smem[25344];

  {
    const uint4* src = (const uint4*)wf;
    uint4* dst = (uint4*)smem;
#pragma unroll
    for (int i = 0; i < 3; i++) dst[threadIdx.x + i * 512] = src[threadIdx.x + i * 512];
    int t = threadIdx.x;
    if (t < 64) {
      ((float*)(smem + 24576))[t] = b1g[t];
      ((float*)(smem + 24832))[t] = b2g[t];
      ((float*)(smem + 25088))[t] = w3g[t];
    }
  }
  __syncthreads();

  const __bf16* w1f = (const __bf16*)smem;
  const __bf16* w2f = (const __bf16*)(smem + 16384);
  const int wid = threadIdx.x >> 6;
  const int l   = threadIdx.x & 63;
  const int g   = l >> 4;
  const int lr  = l & 15;
  const float b3v = b3g[0];

  const int gw = blockIdx.x * 8 + wid;
  const int nwaves = gridDim.x * 8;

  const float4 z4 = make_float4(0.f, 0.f, 0.f, 0.f);
  float4 ru0 = z4, ru1 = z4, ru2 = z4, ru3 = z4;
  float4 re0a = z4, re0b = z4, re0c = z4, re0d = z4;
  float4 re1a = z4, re1b = z4, re1c = z4, re1d = z4;

  int n = gw;
  int cd = 0;
  if (n < N) {
    const int n0 = vn[n];
    cd = nd[n];
    const int j0 = ni[(long)n * 32 + lr];
    const int j1 = ni[(long)n * 32 + 16 + lr];
    ISSUE_RAW(n0, cd, j0, j1);
  }

  for (; n < N; n += nwaves) {
    const bool m1 = (cd > 16);

    // prefetch indices for the NEXT node (issued early; consumed mid-loop)
    int nn = n + nwaves; if (nn >= N) nn = n;
    const int xn = vn[nn], xd = nd[nn];
    const int xi0 = ni[(long)nn * 32 + lr];
    const int xi1 = ni[(long)nn * 32 + 16 + lr];

    int boff = 24576;
    asm volatile("" : "+v"(boff));   // opaque: keep bias reads in LDS, not regs
    const unsigned char* bb = smem + boff;

    if (cd == 0) {                   // fall back to own embedding (exact f32)
      if (lr == 0) {
        float* op = out + (long)n * 64;
        *(float4*)(op + g * 8)      = ru0;
        *(float4*)(op + g * 8 + 4)  = ru1;
        *(float4*)(op + 32 + g * 8) = ru2;
        *(float4*)(op + 36 + g * 8) = ru3;
      }
      ISSUE_RAW(xn, xd, xi0, xi1);
    } else {
      // ---- cvt raw -> bf16 frags (zero padded lanes) ----
      const bool v0c = (lr < cd);
      const bool v1c = m1 && (16 + lr < cd);
      bf16x8 ef00, ef01, ef10, ef11, uf0, uf1;
      {
        float4 a = v0c ? re0a : z4, b = v0c ? re0b : z4;
        float4 c = v0c ? re0c : z4, d = v0c ? re0d : z4;
        ef00 = cvt8(a, b); ef01 = cvt8(c, d);
      }
      if (m1) {
        float4 a = v1c ? re1a : z4, b = v1c ? re1b : z4;
        float4 c = v1c ? re1c : z4, d = v1c ? re1d : z4;
        ef10 = cvt8(a, b); ef11 = cvt8(c, d);
      }
      uf0 = cvt8(ru0, ru1); uf1 = cvt8(ru2, ru3);

      // ---- layer 1: C1t[64][32] = W1^T @ X^T (acc init = b1) ----
      f32x4 acc1[4][2];
#pragma unroll
      for (int mt = 0; mt < 4; mt++) {
        f32x4 bv = *(const f32x4*)(bb + (mt * 16 + g * 4) * 4);
        acc1[mt][0] = bv; acc1[mt][1] = bv;
      }
      const bf16x8 xb0s[4] = {ef00, ef01, uf0, uf1};
      const bf16x8 xb1s[4] = {ef10, ef11, uf0, uf1};
#pragma unroll
      for (int ks = 0; ks < 4; ks++) {
#pragma unroll
        for (int mt = 0; mt < 4; mt++) {
          bf16x8 wa = *(const bf16x8*)(w1f + ((ks * 4 + mt) * 64 + l) * 8);
          MFMA32(acc1[mt][0], wa, xb0s[ks]);
          if (m1) MFMA32(acc1[mt][1], wa, xb1s[ks]);
        }
      }

      // ---- relu -> bf16 B-frags for layer 2 (permuted k-axis, in-register) ----
      bf16x8 hb[2][2];
#pragma unroll
      for (int ks2 = 0; ks2 < 2; ks2++) {
#pragma unroll
        for (int nt = 0; nt < 2; nt++) {
          if (nt == 0 || m1) {
            bf16x8 v;
#pragma unroll
            for (int j = 0; j < 8; j++) {
              const int mt = ks2 * 2 + (j >> 2), r = j & 3;
              v[j] = (__bf16)fmaxf(acc1[mt][nt][r], 0.f);
            }
            hb[ks2][nt] = v;
          }
        }
      }

      // ---- layer 2: C2t[64][32] = W2^T @ H1t (acc init = b2) ----
      f32x4 acc2[4][2];
#pragma unroll
      for (int mt2 = 0; mt2 < 4; mt2++) {
        f32x4 bv = *(const f32x4*)(bb + 256 + (mt2 * 16 + g * 4) * 4);
        acc2[mt2][0] = bv; acc2[mt2][1] = bv;
      }
#pragma unroll
      for (int ks2 = 0; ks2 < 2; ks2++) {
#pragma unroll
        for (int mt2 = 0; mt2 < 4; mt2++) {
          bf16x8 wa = *(const bf16x8*)(w2f + ((ks2 * 4 + mt2) * 64 + l) * 8);
          MFMA32(acc2[mt2][0], wa, hb[ks2][0]);
          if (m1) MFMA32(acc2[mt2][1], wa, hb[ks2][1]);
        }
      }

      // ---- issue NEXT node's gather: in flight across score/softmax/output ----
      ISSUE_RAW(xn, xd, xi0, xi1);

      // ---- scores: s[nb] = relu(C2t+b2) . w3 + b3 ----
      float sv0 = 0.f, sv1 = 0.f;
#pragma unroll
      for (int mt2 = 0; mt2 < 4; mt2++) {
        f32x4 wv = *(const f32x4*)(bb + 512 + (mt2 * 16 + g * 4) * 4);
#pragma unroll
        for (int r = 0; r < 4; r++) {
          sv0 += fmaxf(acc2[mt2][0][r], 0.f) * wv[r];
          if (m1) sv1 += fmaxf(acc2[mt2][1][r], 0.f) * wv[r];
        }
      }
      sv0 += __shfl_xor(sv0, 16); sv0 += __shfl_xor(sv0, 32);
      if (m1) { sv1 += __shfl_xor(sv1, 16); sv1 += __shfl_xor(sv1, 32); }

      const bool w0 = (lr < cd);
      const bool w1v = m1 && (16 + lr < cd);
      sv0 = w0 ? (sv0 + b3v) : -1e30f;
      sv1 = w1v ? (sv1 + b3v) : -1e30f;

      // ---- softmax over 32 neighbors (ror all-reduce within 16 lanes) ----
      float mx = fmaxf(sv0, sv1);
      mx = dpp_fmax<0x128>(mx);
      mx = dpp_fmax<0x124>(mx);
      mx = dpp_fmax<0x122>(mx);
      mx = dpp_fmax<0x121>(mx);

      float p0 = w0 ? __expf(sv0 - mx) : 0.f;
      float p1 = w1v ? __expf(sv1 - mx) : 0.f;
      float sum = p0 + p1;
      sum = dpp_fadd<0x128>(sum);
      sum = dpp_fadd<0x124>(sum);
      sum = dpp_fadd<0x122>(sum);
      sum = dpp_fadd<0x121>(sum);
      const float inv = 1.f / sum;
      const float a0 = p0 * inv, a1 = p1 * inv;

      // ---- out[d] = sum_k att[k]*e[k][d]: packed reduce tree ----
      float o[16];
#pragma unroll
      for (int j = 0; j < 8; j++) {
        float v = a0 * (float)ef00[j];
        if (m1) v += a1 * (float)ef10[j];
        o[j] = v;
        float w = a0 * (float)ef01[j];
        if (m1) w += a1 * (float)ef11[j];
        o[8 + j] = w;
      }
      // stage 16->8 (distance 8, DPP ror8)
      float q8[8];
#pragma unroll
      for (int t = 0; t < 8; t++) {
        const bool up = (lr & 8);
        float sel = up ? o[t + 8] : o[t];
        float oth = up ? o[t] : o[t + 8];
        q8[t] = sel + dpp_mov<0x128>(oth);
      }
      // stage 8->4 (distance 4, shfl_xor)
      float q4[4];
#pragma unroll
      for (int t = 0; t < 4; t++) {
        const bool up = (lr & 4);
        float sel = up ? q8[t + 4] : q8[t];
        float oth = up ? q8[t] : q8[t + 4];
        q4[t] = sel + __shfl_xor(oth, 4);
      }
      // stage 4->2 (distance 2, quad_perm xor2 = 0x4E)
      float q2[2];
#pragma unroll
      for (int t = 0; t < 2; t++) {
        const bool up = (lr & 2);
        float sel = up ? q4[t + 2] : q4[t];
        float oth = up ? q4[t] : q4[t + 2];
        q2[t] = sel + dpp_mov<0x4E>(oth);
      }
      // stage 2->1 (distance 1, quad_perm xor1 = 0xB1)
      {
        const bool up = (lr & 1);
        float sel = up ? q2[1] : q2[0];
        float oth = up ? q2[0] : q2[1];
        float r = sel + dpp_mov<0xB1>(oth);
        // lane lr holds full sum of o[lr]; dim = (lr>>3)*32 + g*8 + (lr&7)
        out[(long)n * 64 + ((lr >> 3) << 5) + g * 8 + (lr & 7)] = r;
      }
    }

    cd = xd;
  }
}

extern "C" void kernel_launch(void* const* d_in, const int* in_sizes, int n_in,
                              void* d_out, int out_size, void* d_ws, size_t ws_size,
                              hipStream_t stream) {
  const float* emb = (const float*)d_in[0];
  const float* W1  = (const float*)d_in[1];
  const float* b1  = (const float*)d_in[2];
  const float* W2  = (const float*)d_in[3];
  const float* b2  = (const float*)d_in[4];
  const float* w3  = (const float*)d_in[5];
  const float* b3  = (const float*)d_in[6];
  const int* vn = (const int*)d_in[7];
  const int* ni = (const int*)d_in[8];
  const int* nd = (const int*)d_in[9];
  float* out = (float*)d_out;
  const int N = in_sizes[7];
  __bf16* wf = (__bf16*)d_ws;   // 24576 B

  prep_frags<<<48, 256, 0, stream>>>(W1, W2, wf);
  graph_agg<<<1024, 512, 0, stream>>>(emb, b1, b2, w3, b3, vn, ni, nd, wf, out, N);
}